// Round 7
// baseline (189.693 us; speedup 1.0000x reference)
//
#include <hip/hip_runtime.h>
#include <math.h>

#define NLEV 5
#define TOPKK 1000
#define NCLS 16
#define NPART 16
#define PART_CAP 256
#define CAND_TOT 2048
#define NTOT 785664u
#define HISTSZ (NLEV * 256)

// level boundaries; sizes: 589824, 147456, 36864, 9216, 2304
// ALL boundaries are multiples of 256 -> a 256-thread block never straddles
__device__ __forceinline__ int find_level(unsigned i, unsigned& loc) {
    if (i < 589824u) { loc = i;            return 0; }
    if (i < 737280u) { loc = i - 589824u;  return 1; }
    if (i < 774144u) { loc = i - 737280u;  return 2; }
    if (i < 783360u) { loc = i - 774144u;  return 3; }
    loc = i - 783360u; return 4;
}

struct Ptrs {
    const float* anc[NLEV];
    const float* cls[NLEV];
    const float* reg[NLEV];
};

// order-preserving float32 -> uint32 (larger uint == larger float)
__device__ __forceinline__ unsigned f2key(float f) {
    unsigned u = __float_as_uint(f);
    return (u & 0x80000000u) ? ~u : (u | 0x80000000u);
}

__device__ __forceinline__ float max4(float4 v) {
    return fmaxf(fmaxf(v.x, v.y), fmaxf(v.z, v.w));
}

// wave-aggregated LDS histogram add: keys concentrate in ~2 top-byte bins,
// so per-lane atomicAdd serializes ~60-deep; ballot-group by bin and let one
// leader add popcount per distinct bin (~2-3 iterations typical).
// Requires ALL 64 lanes of the wave active (full blocks — NTOT % 256 == 0).
__device__ __forceinline__ void lds_hist_add(unsigned* lh, unsigned bin, bool valid) {
    unsigned myb = valid ? bin : 0xFFFFFFFFu;     // sentinel group: no add
    int lane = threadIdx.x & 63;
    unsigned long long unhandled = __ballot(1);
    while (unhandled) {
        int leader = __ffsll(unhandled) - 1;
        unsigned b = __shfl(myb, leader);
        unsigned long long same = __ballot(myb == b);
        if (lane == leader && b != 0xFFFFFFFFu)
            atomicAdd(&lh[b], (unsigned)__popcll(same));
        unhandled &= ~same;
    }
}

// per-block redundant radix select for level l: reduce NPART partials over
// 256 bins, suffix-scan, find bin holding the rem_in-th largest.
// aux[0] <- pf_acc | bin<<shift ; aux[1] <- rem within that bin.
__device__ void level_select(const unsigned* histbase, int l, int shift,
                             unsigned rem_in, unsigned pf_acc,
                             unsigned* s, unsigned* aux) {
    int t = threadIdx.x, r = 255 - t;     // scan over r == suffix over bin
    unsigned c = 0;
    #pragma unroll
    for (int pp = 0; pp < NPART; pp++) c += histbase[pp * HISTSZ + l * 256 + t];
    s[r] = c;
    __syncthreads();
    for (int d = 1; d < 256; d <<= 1) {
        unsigned v = (r >= d) ? s[r - d] : 0u;
        __syncthreads();
        s[r] += v;
        __syncthreads();
    }
    unsigned incl = s[r], above = incl - c;
    if (above < rem_in && rem_in <= incl) {      // exactly one winner thread
        aux[0] = pf_acc | (((unsigned)t) << shift);
        aux[1] = rem_in - above;
    }
    __syncthreads();
}

// keys = sortable(max over 16 logits); 8-bit MSB hist (own level's 256 bins)
__global__ __launch_bounds__(256) void k_keys_hist(Ptrs p, unsigned* keys,
                                                   unsigned* hist) {
    __shared__ unsigned lh[256];
    lh[threadIdx.x] = 0u;
    __syncthreads();
    unsigned i = blockIdx.x * 256u + threadIdx.x;      // NTOT == 3069*256
    unsigned loc; int l = find_level(i, loc);
    const float4* c = (const float4*)(p.cls[l]) + (size_t)loc * 4;
    float4 a = c[0], b = c[1], d = c[2], e = c[3];
    float m = max4(a);
    m = fmaxf(m, max4(b));
    m = fmaxf(m, max4(d));
    m = fmaxf(m, max4(e));
    unsigned k = f2key(m);
    keys[i] = k;
    lds_hist_add(lh, k >> 24, true);
    __syncthreads();
    unsigned part = blockIdx.x & (NPART - 1);
    if (lh[threadIdx.x])
        atomicAdd(&hist[part * HISTSZ + l * 256 + threadIdx.x], lh[threadIdx.x]);
}

// inline select-1 from histA, then hist byte [16:23] of matching keys
__global__ __launch_bounds__(256) void k_hist2(const unsigned* keys,
                                               const unsigned* histA,
                                               unsigned* histB) {
    __shared__ unsigned s[256];
    __shared__ unsigned lh[256];
    __shared__ unsigned aux[2];
    unsigned i0 = blockIdx.x * 256u;
    unsigned loc0; int l = find_level(i0, loc0);
    level_select(histA, l, 24, TOPKK, 0u, s, aux);
    unsigned pf = aux[0];
    lh[threadIdx.x] = 0u;
    __syncthreads();
    unsigned k = keys[i0 + threadIdx.x];
    lds_hist_add(lh, (k >> 16) & 0xFFu, (k & 0xFF000000u) == pf);
    __syncthreads();
    unsigned part = blockIdx.x & (NPART - 1);
    if (lh[threadIdx.x])
        atomicAdd(&histB[part * HISTSZ + l * 256 + threadIdx.x], lh[threadIdx.x]);
}

// inline select-1 + select-2, then compact keys >= 16-bit floor
__global__ __launch_bounds__(256) void k_compact(const unsigned* keys,
                                                 const unsigned* histA,
                                                 const unsigned* histB,
                                                 unsigned* cnt,
                                                 unsigned long long* cand) {
    __shared__ unsigned s[256];
    __shared__ unsigned aux[2];
    unsigned i0 = blockIdx.x * 256u;
    unsigned loc0; int l = find_level(i0, loc0);
    level_select(histA, l, 24, TOPKK, 0u, s, aux);
    unsigned pf1 = aux[0], rem1 = aux[1];
    __syncthreads();
    level_select(histB, l, 16, rem1, pf1, s, aux);
    unsigned thresh = aux[0];                 // low 16 bits are zero
    unsigned k = keys[i0 + threadIdx.x];
    if (k >= thresh) {
        unsigned loc = loc0 + threadIdx.x;
        unsigned part = blockIdx.x & (NPART - 1);
        unsigned slot = atomicAdd(&cnt[l * NPART + part], 1u);
        if (slot < PART_CAP)
            cand[((size_t)(l * NPART + part)) * PART_CAP + slot] =
                ((unsigned long long)k << 32) | (unsigned)(~loc);
    }
}

// 8 blocks/level: stage candidates in LDS, rank-by-counting (composite desc
// == key desc, index asc == lax.top_k tie rule; ranks unique since index
// bits differ), winners decode box + write their 16 output rows directly
__global__ __launch_bounds__(256) void k_rank_emit(Ptrs p, const unsigned* cnt,
                                                   const unsigned long long* cand,
                                                   float* out) {
    const float MAXD = 4.135166556742356f;   // log(1000/16)
    int l = blockIdx.x >> 3;
    unsigned sl = blockIdx.x & 7;
    int t = threadIdx.x;
    __shared__ __align__(16) unsigned long long lbuf[CAND_TOT];
    __shared__ unsigned aux[33];

    if (t < NPART) {
        unsigned cc = cnt[l * NPART + t];
        aux[t] = (cc > PART_CAP) ? PART_CAP : cc;
    }
    for (int i = t; i < CAND_TOT; i += 256) lbuf[i] = 0ULL;  // pad for vec scan
    __syncthreads();
    if (t == 0) {
        unsigned o = 0;
        for (int pp = 0; pp < NPART; pp++) { aux[16 + pp] = o; o += aux[pp]; }
        aux[32] = (o > CAND_TOT) ? CAND_TOT : o;
    }
    __syncthreads();
    unsigned n = aux[32];
    for (int pp = 0; pp < NPART; pp++) {
        unsigned cc = aux[pp], o = aux[16 + pp];
        for (unsigned e = t; e < cc; e += 256) {
            unsigned dst = o + e;
            if (dst < CAND_TOT)
                lbuf[dst] = cand[((size_t)(l * NPART + pp)) * PART_CAP + e];
        }
    }
    __syncthreads();

    unsigned j = sl * 256u + t;
    if (j >= n) return;
    unsigned long long my = lbuf[j];
    // vectorized wave-uniform LDS scan (ds_read_b128, broadcast); zero pads
    // never outrank a real composite (keys have MSB context >= 0x3F......)
    const ulonglong2* lb2 = (const ulonglong2*)lbuf;
    unsigned nh = (n + 1) >> 1;
    unsigned rank = 0;
    #pragma unroll 4
    for (unsigned q = 0; q < nh; q++) {
        ulonglong2 v = lb2[q];
        rank += (v.x > my) ? 1u : 0u;
        rank += (v.y > my) ? 1u : 0u;
    }
    if (rank >= TOPKK) return;

    unsigned idx = ~((unsigned)(my & 0xFFFFFFFFull));
    float4 an = ((const float4*)p.anc[l])[idx];
    float4 dd = ((const float4*)p.reg[l])[(size_t)idx * 2];
    float w = an.z - an.x, h = an.w - an.y;
    float cx = an.x + 0.5f * w, cy = an.y + 0.5f * h;
    float pcx = cx + dd.x * w, pcy = cy + dd.y * h;
    float pw = w * expf(fminf(dd.z, MAXD));
    float ph = h * expf(fminf(dd.w, MAXD));
    float bx = pcx - 0.5f * pw, by = pcy - 0.5f * ph;
    float bz = pcx + 0.5f * pw, bw = pcy + 0.5f * ph;

    const float4* cp = (const float4*)(p.cls[l]) + (size_t)idx * 4;
    float sg[16];
    #pragma unroll
    for (int g = 0; g < 4; g++) {
        float4 v = cp[g];
        sg[4 * g + 0] = 1.0f / (1.0f + expf(-v.x));
        sg[4 * g + 1] = 1.0f / (1.0f + expf(-v.y));
        sg[4 * g + 2] = 1.0f / (1.0f + expf(-v.z));
        sg[4 * g + 3] = 1.0f / (1.0f + expf(-v.w));
    }
    // 16 rows of [bx,by,bz,bw,score,tag] == 24 float4s, 384B contiguous
    float4* q = (float4*)(out + (size_t)(l * TOPKK + rank) * (NCLS * 6));
    #pragma unroll
    for (int g = 0; g < 8; g++) {
        float ta = (float)(2 * g + 1), tb = (float)(2 * g + 2);
        q[3 * g + 0] = make_float4(bx, by, bz, bw);
        q[3 * g + 1] = make_float4(sg[2 * g], ta, bx, by);
        q[3 * g + 2] = make_float4(bz, bw, sg[2 * g + 1], tb);
    }
}

extern "C" void kernel_launch(void* const* d_in, const int* in_sizes, int n_in,
                              void* d_out, int out_size, void* d_ws, size_t ws_size,
                              hipStream_t stream) {
    Ptrs p;
    for (int l = 0; l < NLEV; l++) {
        p.anc[l] = (const float*)d_in[3 * l + 0];
        p.cls[l] = (const float*)d_in[3 * l + 1];
        p.reg[l] = (const float*)d_in[3 * l + 2];
    }
    char* w = (char*)d_ws;
    // layout (bytes):
    //   keys   : 0        .. 3142656   (785664 u32)
    //   histA  : 3142656  .. +81920    \
    //   histB  : 3224576  .. +81920     } one contiguous memset (164160 B)
    //   cnt    : 3306496  .. +320      /
    //   cand   : 3306816  .. +163840
    unsigned* keys  = (unsigned*)w;
    unsigned* histA = (unsigned*)(w + 3142656);
    unsigned* histB = (unsigned*)(w + 3224576);
    unsigned* cnt   = (unsigned*)(w + 3306496);
    unsigned long long* cand = (unsigned long long*)(w + 3306816);

    float* out = (float*)d_out;
    int nb = NTOT / 256;                     // 3069, exact

    (void)hipMemsetAsync(histA, 0, 164160, stream);
    k_keys_hist<<<nb, 256, 0, stream>>>(p, keys, histA);
    k_hist2<<<nb, 256, 0, stream>>>(keys, histA, histB);
    k_compact<<<nb, 256, 0, stream>>>(keys, histA, histB, cnt, cand);
    k_rank_emit<<<NLEV * 8, 256, 0, stream>>>(p, cnt, cand, out);
}